// Round 8
// baseline (369.462 us; speedup 1.0000x reference)
//
#include <hip/hip_runtime.h>

typedef short bf16x8 __attribute__((ext_vector_type(8)));
typedef float f32x4 __attribute__((ext_vector_type(4)));

__device__ __forceinline__ unsigned short f2bf(float f) {
    unsigned u = __float_as_uint(f);
    unsigned r = (u + 0x7fffu + ((u >> 16) & 1u)) >> 16;
    return (unsigned short)r;
}

// ---------------- CSR build ----------------
__global__ void k_hist(const int* __restrict__ ei, int E, int* deg) {
    int e = blockIdx.x * blockDim.x + threadIdx.x;
    if (e < E) atomicAdd(&deg[ei[E + e]], 1);
}
__global__ void k_scan(const int* __restrict__ deg, int* __restrict__ off,
                       int* __restrict__ cur, int N) {
    __shared__ int sums[1024];
    int t = threadIdx.x;
    int chunk = (N + 1023) >> 10;
    int lo = t * chunk;
    int hi = lo + chunk; if (hi > N) hi = N;
    if (lo > N) lo = N;
    int s = 0;
    for (int i = lo; i < hi; ++i) s += deg[i];
    sums[t] = s;
    __syncthreads();
    for (int dd = 1; dd < 1024; dd <<= 1) {
        int v = (t >= dd) ? sums[t - dd] : 0;
        __syncthreads();
        sums[t] += v;
        __syncthreads();
    }
    int run = sums[t] - s;  // exclusive prefix
    for (int i = lo; i < hi; ++i) { off[i] = run; cur[i] = run; run += deg[i]; }
    if (t == 1023) off[N] = run;
}
__global__ void k_fill(const int* __restrict__ ei, int E, int N,
                       int* cur, int* __restrict__ csr) {
    int i = blockIdx.x * blockDim.x + threadIdx.x;
    if (i < E) {
        int s = ei[i], d = ei[E + i];
        int pos = atomicAdd(&cur[d], 1);
        csr[pos] = s;
    } else if (i < E + N) {
        int nn = i - E;
        int pos = atomicAdd(&cur[nn], 1);
        csr[pos] = nn;
    }
}

// ---------------- fused prep: W transposes (f32->bf16), x cvt, deg init ----
__global__ void k_prep(const float* __restrict__ W1, unsigned short* __restrict__ W1T,
                       const float* __restrict__ W2, unsigned short* __restrict__ W2T,
                       const float* __restrict__ W3, unsigned short* __restrict__ W3T,
                       const float* __restrict__ x, unsigned short* __restrict__ xb,
                       int* __restrict__ deg,
                       int DIN, int HC, int DOUT, int N)
{
    int i = blockIdx.x * blockDim.x + threadIdx.x;
    int n1 = DIN * HC;            // W1: [DIN,HC] -> [HC,DIN]
    int n2 = n1 + HC * HC;
    int n3 = n2 + HC * DOUT;
    int n4 = n3 + N * DIN;
    int n5 = n4 + N;
    if (i < n1) {
        int k = i / HC, n = i - k * HC;
        W1T[n * DIN + k] = f2bf(W1[i]);
    } else if (i < n2) {
        int j = i - n1;
        int k = j / HC, n = j - k * HC;
        W2T[n * HC + k] = f2bf(W2[j]);
    } else if (i < n3) {
        int j = i - n2;
        int k = j / DOUT, n = j - k * DOUT;
        W3T[n * HC + k] = f2bf(W3[j]);
    } else if (i < n4) {
        int j = i - n3;
        xb[j] = f2bf(x[j]);
    } else if (i < n5) {
        deg[i - n4] = 1;  // self-loop
    }
}

// ---------------- GEMM: D[M,Nc] = A[M,K] (bf16) @ BT[Nc,K]^T (bf16) ----
// one wave computes a 64x64 tile; register double-buffered K loop
template <bool OUTBF>
__global__ __launch_bounds__(256) void k_gemm(
    const unsigned short* __restrict__ A, const unsigned short* __restrict__ BT,
    void* __restrict__ D, int M, int K, int Nc, int tiles_n)
{
    int wid = blockIdx.x * (blockDim.x >> 6) + (threadIdx.x >> 6);
    int tiles_m = (M + 63) >> 6;
    if (wid >= tiles_m * tiles_n) return;
    int lane = threadIdx.x & 63;
    int tm = wid / tiles_n, tn = wid - tm * tiles_n;
    int m0 = tm << 6, n0 = tn << 6;
    int r = lane & 15, q = lane >> 4;

    const unsigned short* Arow[4];
    const unsigned short* Brow[4];
#pragma unroll
    for (int i = 0; i < 4; ++i) {
        int row = m0 + 16 * i + r; row = row < M ? row : M - 1;
        Arow[i] = A + (size_t)row * K + q * 8;
        Brow[i] = BT + (size_t)(n0 + 16 * i + r) * K + q * 8;
    }

    f32x4 acc[4][4] = {};
    bf16x8 a[4], b[4], a2[4], b2[4];
#pragma unroll
    for (int i = 0; i < 4; ++i) {
        a[i] = *(const bf16x8*)(Arow[i]);
        b[i] = *(const bf16x8*)(Brow[i]);
    }
    for (int k0 = 0; k0 < K; k0 += 32) {
        int kn = k0 + 32;
        if (kn < K) {
#pragma unroll
            for (int i = 0; i < 4; ++i) {
                a2[i] = *(const bf16x8*)(Arow[i] + kn);
                b2[i] = *(const bf16x8*)(Brow[i] + kn);
            }
        }
#pragma unroll
        for (int i = 0; i < 4; ++i)
#pragma unroll
            for (int j = 0; j < 4; ++j)
                acc[i][j] = __builtin_amdgcn_mfma_f32_16x16x32_bf16(a[i], b[j], acc[i][j], 0, 0, 0);
        if (kn < K) {
#pragma unroll
            for (int i = 0; i < 4; ++i) { a[i] = a2[i]; b[i] = b2[i]; }
        }
    }
#pragma unroll
    for (int i = 0; i < 4; ++i) {
        int rowb = m0 + 16 * i + q * 4;
#pragma unroll
        for (int rr = 0; rr < 4; ++rr) {
            int row = rowb + rr;
            if (row < M) {
#pragma unroll
                for (int j = 0; j < 4; ++j) {
                    int col = n0 + 16 * j + r;
                    if (OUTBF)
                        ((unsigned short*)D)[(size_t)row * Nc + col] = f2bf(acc[i][j][rr]);
                    else
                        ((float*)D)[(size_t)row * Nc + col] = acc[i][j][rr];
                }
            }
        }
    }
}

// ---------------- attention logits per node: al_s, al_d -------------------
template <int HCt, int Ht, bool INBF>
__global__ __launch_bounds__(256) void k_al(
    const void* __restrict__ h, const float* __restrict__ asrc,
    const float* __restrict__ adst,
    float* __restrict__ als, float* __restrict__ ald, int N)
{
    int wid = blockIdx.x * (blockDim.x >> 6) + (threadIdx.x >> 6);
    if (wid >= N) return;
    int lane = threadIdx.x & 63;
    const int CH = HCt / 64;
    const int Gs = 64 / Ht;  // lanes per head
    float s = 0.f, d = 0.f;
    if constexpr (INBF) {
        // CH == 8: one 16B load of 8 bf16
        const uint4* hr = (const uint4*)((const unsigned short*)h + (size_t)wid * HCt) + lane;
        uint4 hv = *hr;
        unsigned wds[4] = {hv.x, hv.y, hv.z, hv.w};
        const f32x4* as4 = (const f32x4*)(asrc + lane * 8);
        const f32x4* ad4 = (const f32x4*)(adst + lane * 8);
        f32x4 av0 = as4[0], av1 = as4[1], dv0 = ad4[0], dv1 = ad4[1];
        float hf[8];
#pragma unroll
        for (int wv = 0; wv < 4; ++wv) {
            hf[2 * wv]     = __uint_as_float(wds[wv] << 16);
            hf[2 * wv + 1] = __uint_as_float(wds[wv] & 0xffff0000u);
        }
#pragma unroll
        for (int j = 0; j < 4; ++j) {
            s += hf[j] * av0[j] + hf[4 + j] * av1[j];
            d += hf[j] * dv0[j] + hf[4 + j] * dv1[j];
        }
    } else {
        const float* hr = (const float*)h + (size_t)wid * HCt + lane * CH;
#pragma unroll
        for (int j = 0; j < CH; ++j) {
            float hv = hr[j];
            int ch = lane * CH + j;
            s += hv * asrc[ch];
            d += hv * adst[ch];
        }
    }
#pragma unroll
    for (int dd = 1; dd < Gs; dd <<= 1) {
        s += __shfl_xor(s, dd);
        d += __shfl_xor(d, dd);
    }
    if ((lane & (Gs - 1)) == 0) {
        int hh = lane / Gs;
        als[wid * Ht + hh] = s;
        ald[wid * Ht + hh] = d;
    }
}

// ---------------- aggr for HC=512, H=4, bf16 h ----------------------------
// No max-subtraction (softmax shift-invariant; logits bounded ~|10| here,
// far inside f32 exp range). Wave = (node, sub) where sub = head*2 + half:
// 8 edge-groups x 8 lanes, lane owns 8 contiguous bf16 (16B) of a 64-ch
// half-head slice. Slab-sequential grid: all nodes for sub 0, then sub 1...
// -> 1.25 MB distinct h lines per slab, L2-resident per XCD.
template <bool DOELU>
__global__ __launch_bounds__(256) void k_aggr8(
    const unsigned short* __restrict__ h, const float* __restrict__ als,
    const float* __restrict__ aldv, const int* __restrict__ off,
    const int* __restrict__ csr, const float* __restrict__ bias,
    unsigned short* __restrict__ outp, int N, int nodeBlocks)
{
    int sub = blockIdx.x / nodeBlocks;   // 0..7 = head*2 + half
    int nb = blockIdx.x - sub * nodeBlocks;
    int n = nb * 4 + (threadIdx.x >> 6);
    if (n >= N) return;
    int head = sub >> 1, half = sub & 1;
    int lane = threadIdx.x & 63;
    int g = lane >> 3;            // edge group 0..7
    int p = lane & 7;             // channel-lane within group
    int s0 = off[n], s1 = off[n + 1];
    float aldh = aldv[n * 4 + head];

    float acc[8] = {};
    float den = 0.f;
    const unsigned short* hbase = h + head * 128 + half * 64 + p * 8;

    auto stage = [&](int tt, float& e, uint4& q) {
        int ss = csr[tt];
        float l = als[ss * 4 + head] + aldh;
        l = l > 0.f ? l : 0.2f * l;
        e = __expf(l);
        q = *(const uint4*)(hbase + (size_t)ss * 512);
    };

    // depth-2 software pipeline, 8 edges in flight per stage
    int t = s0 + g;
    float ex; uint4 hq;
    bool have = t < s1;
    if (have) stage(t, ex, hq);
    while (have) {
        int tn = t + 8;
        float ex2; uint4 hq2;
        bool have2 = tn < s1;
        if (have2) stage(tn, ex2, hq2);
        den += ex;
        unsigned wds[4] = {hq.x, hq.y, hq.z, hq.w};
#pragma unroll
        for (int wv = 0; wv < 4; ++wv) {
            acc[2 * wv]     += ex * __uint_as_float(wds[wv] << 16);
            acc[2 * wv + 1] += ex * __uint_as_float(wds[wv] & 0xffff0000u);
        }
        t = tn; have = have2; ex = ex2; hq = hq2;
    }

    // reduce across the 8 edge groups (lanes with same p)
    den += __shfl_xor(den, 8);
    den += __shfl_xor(den, 16);
    den += __shfl_xor(den, 32);
#pragma unroll
    for (int j = 0; j < 8; ++j) {
        acc[j] += __shfl_xor(acc[j], 8);
        acc[j] += __shfl_xor(acc[j], 16);
        acc[j] += __shfl_xor(acc[j], 32);
    }

    if (g == 0) {
        float inv = 1.f / den;
        int cb = head * 128 + half * 64 + p * 8;
        unsigned ww[4];
#pragma unroll
        for (int wv = 0; wv < 4; ++wv) {
            float v0 = acc[2 * wv] * inv + bias[cb + 2 * wv];
            float v1 = acc[2 * wv + 1] * inv + bias[cb + 2 * wv + 1];
            if (DOELU) {
                v0 = v0 > 0.f ? v0 : expm1f(v0);
                v1 = v1 > 0.f ? v1 : expm1f(v1);
            }
            ww[wv] = (unsigned)f2bf(v0) | ((unsigned)f2bf(v1) << 16);
        }
        uint4 o; o.x = ww[0]; o.y = ww[1]; o.z = ww[2]; o.w = ww[3];
        *((uint4*)(outp + (size_t)n * 512 + cb)) = o;
    }
}

// ---------------- generic aggr (layer 3: HC=64, H=1, f32 in/out) ----------
// one wave per dst node; 4 edge-groups x 16 lanes; lane owns 4 f32 (16B).
// No max-subtraction (see k_aggr8 note).
template <int HCt, bool DOELU>
__global__ __launch_bounds__(256) void k_aggr(
    const float* __restrict__ h, const float* __restrict__ als,
    const float* __restrict__ aldv, const int* __restrict__ off,
    const int* __restrict__ csr, const float* __restrict__ bias,
    float* __restrict__ outp, int N)
{
    int n = blockIdx.x * (blockDim.x >> 6) + (threadIdx.x >> 6);
    if (n >= N) return;
    int lane = threadIdx.x & 63;
    int g = lane >> 4;        // edge group 0..3
    int p = lane & 15;        // channel-lane within group
    const int CH = HCt / 16;  // 4 f32 per lane
    int s0 = off[n], s1 = off[n + 1];
    float aldh = aldv[n];

    float acc[CH] = {};
    float den = 0.f;
    auto stage = [&](int tt, float& e, uint4& q) {
        int ss = csr[tt];
        float l = als[ss] + aldh;
        l = l > 0.f ? l : 0.2f * l;
        e = __expf(l);
        q = *((const uint4*)(h + (size_t)ss * HCt) + p);
    };
    int t = s0 + g;
    float ex; uint4 hq;
    bool have = t < s1;
    if (have) stage(t, ex, hq);
    while (have) {
        int tn = t + 4;
        float ex2; uint4 hq2;
        bool have2 = tn < s1;
        if (have2) stage(tn, ex2, hq2);
        den += ex;
        acc[0] += ex * __uint_as_float(hq.x);
        acc[1] += ex * __uint_as_float(hq.y);
        acc[2] += ex * __uint_as_float(hq.z);
        acc[3] += ex * __uint_as_float(hq.w);
        t = tn; have = have2; ex = ex2; hq = hq2;
    }

    den += __shfl_xor(den, 16);
    den += __shfl_xor(den, 32);
#pragma unroll
    for (int j = 0; j < CH; ++j) {
        acc[j] += __shfl_xor(acc[j], 16);
        acc[j] += __shfl_xor(acc[j], 32);
    }
    if (g == 0) {
        float inv = 1.f / den;
        f32x4 o;
#pragma unroll
        for (int j = 0; j < 4; ++j) {
            float v = acc[j] * inv + bias[p * 4 + j];
            if (DOELU) v = v > 0.f ? v : expm1f(v);
            o[j] = v;
        }
        *((f32x4*)(outp + (size_t)n * HCt + p * 4)) = o;
    }
}

// --------------------------------------------------------------------------
extern "C" void kernel_launch(void* const* d_in, const int* in_sizes, int n_in,
                              void* d_out, int out_size, void* d_ws, size_t ws_size,
                              hipStream_t stream)
{
    const float* x   = (const float*)d_in[0];
    const int*   ei  = (const int*)d_in[1];
    const float* W1  = (const float*)d_in[2];
    const float* as1 = (const float*)d_in[3];
    const float* ad1 = (const float*)d_in[4];
    const float* b1  = (const float*)d_in[5];
    const float* W2  = (const float*)d_in[6];
    const float* as2 = (const float*)d_in[7];
    const float* ad2 = (const float*)d_in[8];
    const float* b2  = (const float*)d_in[9];
    const float* W3  = (const float*)d_in[10];
    const float* as3 = (const float*)d_in[11];
    const float* ad3 = (const float*)d_in[12];
    const float* b3  = (const float*)d_in[13];

    const int DIN = 256, HC = 512, DOUT = 64;
    int N = in_sizes[0] / DIN;
    int E = in_sizes[1] / 2;

    // workspace carve-up
    char* w = (char*)d_ws;
    auto alloc = [&](size_t bytes) -> char* {
        char* p = w;
        w += (bytes + 255) & ~(size_t)255;
        return p;
    };
    int* deg   = (int*)alloc((size_t)N * 4);
    int* cur   = (int*)alloc((size_t)N * 4);
    int* off   = (int*)alloc((size_t)(N + 1) * 4);
    int* csr   = (int*)alloc((size_t)(E + N) * 4);
    unsigned short* W1T = (unsigned short*)alloc((size_t)HC * DIN * 2);
    unsigned short* W2T = (unsigned short*)alloc((size_t)HC * HC * 2);
    unsigned short* W3T = (unsigned short*)alloc((size_t)DOUT * HC * 2);
    unsigned short* xb  = (unsigned short*)alloc((size_t)N * DIN * 2);  // bf16 GEMM A (layer1)
    unsigned short* act = (unsigned short*)alloc((size_t)N * HC * 2);   // bf16 activations
    unsigned short* hb  = (unsigned short*)alloc((size_t)N * HC * 2);   // bf16 h (layers 1-2)
    float* hbuf = (float*)alloc((size_t)N * DOUT * 4);                  // f32 h (layer 3)
    float* als  = (float*)alloc((size_t)N * 4 * 4);
    float* ald  = (float*)alloc((size_t)N * 4 * 4);

    // ---- prep (transposes + cvt + deg init), then CSR ----
    int prep_total = DIN * HC + HC * HC + HC * DOUT + N * DIN + N;
    k_prep<<<(prep_total + 255) / 256, 256, 0, stream>>>(
        W1, W1T, W2, W2T, W3, W3T, x, xb, deg, DIN, HC, DOUT, N);
    k_hist<<<(E + 255) / 256, 256, 0, stream>>>(ei, E, deg);
    k_scan<<<1, 1024, 0, stream>>>(deg, off, cur, N);
    k_fill<<<(E + N + 255) / 256, 256, 0, stream>>>(ei, E, N, cur, csr);

    int tiles_m = (N + 63) / 64;
    auto gemm_blocks = [&](int tn) { return (tiles_m * tn + 3) / 4; };
    int nwave_blocks = (N + 3) / 4;
    int nodeBlocks = (N + 3) / 4;

    // ---- layer 1 ----
    k_gemm<true><<<gemm_blocks(HC / 64), 256, 0, stream>>>(xb, W1T, hb, N, DIN, HC, HC / 64);
    k_al<512, 4, true><<<nwave_blocks, 256, 0, stream>>>(hb, as1, ad1, als, ald, N);
    k_aggr8<true><<<8 * nodeBlocks, 256, 0, stream>>>(hb, als, ald, off, csr, b1, act, N, nodeBlocks);

    // ---- layer 2 ----
    k_gemm<true><<<gemm_blocks(HC / 64), 256, 0, stream>>>(act, W2T, hb, N, HC, HC, HC / 64);
    k_al<512, 4, true><<<nwave_blocks, 256, 0, stream>>>(hb, as2, ad2, als, ald, N);
    k_aggr8<true><<<8 * nodeBlocks, 256, 0, stream>>>(hb, als, ald, off, csr, b2, act, N, nodeBlocks);

    // ---- layer 3 ----
    k_gemm<false><<<gemm_blocks(1), 256, 0, stream>>>(act, W3T, hbuf, N, HC, DOUT, 1);
    k_al<64, 1, false><<<nwave_blocks, 256, 0, stream>>>(hbuf, as3, ad3, als, ald, N);
    k_aggr<64, false><<<nwave_blocks, 256, 0, stream>>>(
        hbuf, als, ald, off, csr, b3, (float*)d_out, N);
}

// Round 9
// 349.384 us; speedup vs baseline: 1.0575x; 1.0575x over previous
//
#include <hip/hip_runtime.h>

typedef short bf16x8 __attribute__((ext_vector_type(8)));
typedef float f32x4 __attribute__((ext_vector_type(4)));

__device__ __forceinline__ unsigned short f2bf(float f) {
    unsigned u = __float_as_uint(f);
    unsigned r = (u + 0x7fffu + ((u >> 16) & 1u)) >> 16;
    return (unsigned short)r;
}

// ---------------- CSR build ----------------
__global__ void k_hist(const int* __restrict__ ei, int E, int* deg) {
    int e = blockIdx.x * blockDim.x + threadIdx.x;
    if (e < E) atomicAdd(&deg[ei[E + e]], 1);
}
__global__ void k_scan(const int* __restrict__ deg, int* __restrict__ off,
                       int* __restrict__ cur, int N) {
    __shared__ int sums[1024];
    int t = threadIdx.x;
    int chunk = (N + 1023) >> 10;
    int lo = t * chunk;
    int hi = lo + chunk; if (hi > N) hi = N;
    if (lo > N) lo = N;
    int s = 0;
    for (int i = lo; i < hi; ++i) s += deg[i];
    sums[t] = s;
    __syncthreads();
    for (int dd = 1; dd < 1024; dd <<= 1) {
        int v = (t >= dd) ? sums[t - dd] : 0;
        __syncthreads();
        sums[t] += v;
        __syncthreads();
    }
    int run = sums[t] - s;  // exclusive prefix
    for (int i = lo; i < hi; ++i) { off[i] = run; cur[i] = run; run += deg[i]; }
    if (t == 1023) off[N] = run;
}
__global__ void k_fill(const int* __restrict__ ei, int E, int N,
                       int* cur, int* __restrict__ csr, int* __restrict__ dstarr) {
    int i = blockIdx.x * blockDim.x + threadIdx.x;
    if (i < E) {
        int s = ei[i], d = ei[E + i];
        int pos = atomicAdd(&cur[d], 1);
        csr[pos] = s;
        dstarr[pos] = d;
    } else if (i < E + N) {
        int nn = i - E;
        int pos = atomicAdd(&cur[nn], 1);
        csr[pos] = nn;
        dstarr[pos] = nn;
    }
}

// ---------------- fused prep: W transposes (f32->bf16), x cvt, deg init ----
__global__ void k_prep(const float* __restrict__ W1, unsigned short* __restrict__ W1T,
                       const float* __restrict__ W2, unsigned short* __restrict__ W2T,
                       const float* __restrict__ W3, unsigned short* __restrict__ W3T,
                       const float* __restrict__ x, unsigned short* __restrict__ xb,
                       int* __restrict__ deg,
                       int DIN, int HC, int DOUT, int N)
{
    int i = blockIdx.x * blockDim.x + threadIdx.x;
    int n1 = DIN * HC;            // W1: [DIN,HC] -> [HC,DIN]
    int n2 = n1 + HC * HC;
    int n3 = n2 + HC * DOUT;
    int n4 = n3 + N * DIN;
    int n5 = n4 + N;
    if (i < n1) {
        int k = i / HC, n = i - k * HC;
        W1T[n * DIN + k] = f2bf(W1[i]);
    } else if (i < n2) {
        int j = i - n1;
        int k = j / HC, n = j - k * HC;
        W2T[n * HC + k] = f2bf(W2[j]);
    } else if (i < n3) {
        int j = i - n2;
        int k = j / DOUT, n = j - k * DOUT;
        W3T[n * HC + k] = f2bf(W3[j]);
    } else if (i < n4) {
        int j = i - n3;
        xb[j] = f2bf(x[j]);
    } else if (i < n5) {
        deg[i - n4] = 1;  // self-loop
    }
}

// ---------------- GEMM: D[M,Nc] = A[M,K] (bf16) @ BT[Nc,K]^T (bf16) ----
// one wave computes a 64x64 tile; register double-buffered K loop
template <bool OUTBF>
__global__ __launch_bounds__(256) void k_gemm(
    const unsigned short* __restrict__ A, const unsigned short* __restrict__ BT,
    void* __restrict__ D, int M, int K, int Nc, int tiles_n)
{
    int wid = blockIdx.x * (blockDim.x >> 6) + (threadIdx.x >> 6);
    int tiles_m = (M + 63) >> 6;
    if (wid >= tiles_m * tiles_n) return;
    int lane = threadIdx.x & 63;
    int tm = wid / tiles_n, tn = wid - tm * tiles_n;
    int m0 = tm << 6, n0 = tn << 6;
    int r = lane & 15, q = lane >> 4;

    const unsigned short* Arow[4];
    const unsigned short* Brow[4];
#pragma unroll
    for (int i = 0; i < 4; ++i) {
        int row = m0 + 16 * i + r; row = row < M ? row : M - 1;
        Arow[i] = A + (size_t)row * K + q * 8;
        Brow[i] = BT + (size_t)(n0 + 16 * i + r) * K + q * 8;
    }

    f32x4 acc[4][4] = {};
    bf16x8 a[4], b[4], a2[4], b2[4];
#pragma unroll
    for (int i = 0; i < 4; ++i) {
        a[i] = *(const bf16x8*)(Arow[i]);
        b[i] = *(const bf16x8*)(Brow[i]);
    }
    for (int k0 = 0; k0 < K; k0 += 32) {
        int kn = k0 + 32;
        if (kn < K) {
#pragma unroll
            for (int i = 0; i < 4; ++i) {
                a2[i] = *(const bf16x8*)(Arow[i] + kn);
                b2[i] = *(const bf16x8*)(Brow[i] + kn);
            }
        }
#pragma unroll
        for (int i = 0; i < 4; ++i)
#pragma unroll
            for (int j = 0; j < 4; ++j)
                acc[i][j] = __builtin_amdgcn_mfma_f32_16x16x32_bf16(a[i], b[j], acc[i][j], 0, 0, 0);
        if (kn < K) {
#pragma unroll
            for (int i = 0; i < 4; ++i) { a[i] = a2[i]; b[i] = b2[i]; }
        }
    }
#pragma unroll
    for (int i = 0; i < 4; ++i) {
        int rowb = m0 + 16 * i + q * 4;
#pragma unroll
        for (int rr = 0; rr < 4; ++rr) {
            int row = rowb + rr;
            if (row < M) {
#pragma unroll
                for (int j = 0; j < 4; ++j) {
                    int col = n0 + 16 * j + r;
                    if (OUTBF)
                        ((unsigned short*)D)[(size_t)row * Nc + col] = f2bf(acc[i][j][rr]);
                    else
                        ((float*)D)[(size_t)row * Nc + col] = acc[i][j][rr];
                }
            }
        }
    }
}

// ---------------- attention logits per node: al_s, al_d -------------------
template <int HCt, int Ht, bool INBF>
__global__ __launch_bounds__(256) void k_al(
    const void* __restrict__ h, const float* __restrict__ asrc,
    const float* __restrict__ adst,
    float* __restrict__ als, float* __restrict__ ald, int N)
{
    int wid = blockIdx.x * (blockDim.x >> 6) + (threadIdx.x >> 6);
    if (wid >= N) return;
    int lane = threadIdx.x & 63;
    const int CH = HCt / 64;
    const int Gs = 64 / Ht;  // lanes per head
    float s = 0.f, d = 0.f;
    if constexpr (INBF) {
        // CH == 8: one 16B load of 8 bf16
        const uint4* hr = (const uint4*)((const unsigned short*)h + (size_t)wid * HCt) + lane;
        uint4 hv = *hr;
        unsigned wds[4] = {hv.x, hv.y, hv.z, hv.w};
        const f32x4* as4 = (const f32x4*)(asrc + lane * 8);
        const f32x4* ad4 = (const f32x4*)(adst + lane * 8);
        f32x4 av0 = as4[0], av1 = as4[1], dv0 = ad4[0], dv1 = ad4[1];
        float hf[8];
#pragma unroll
        for (int wv = 0; wv < 4; ++wv) {
            hf[2 * wv]     = __uint_as_float(wds[wv] << 16);
            hf[2 * wv + 1] = __uint_as_float(wds[wv] & 0xffff0000u);
        }
#pragma unroll
        for (int j = 0; j < 4; ++j) {
            s += hf[j] * av0[j] + hf[4 + j] * av1[j];
            d += hf[j] * dv0[j] + hf[4 + j] * dv1[j];
        }
    } else {
        const float* hr = (const float*)h + (size_t)wid * HCt + lane * CH;
#pragma unroll
        for (int j = 0; j < CH; ++j) {
            float hv = hr[j];
            int ch = lane * CH + j;
            s += hv * asrc[ch];
            d += hv * adst[ch];
        }
    }
#pragma unroll
    for (int dd = 1; dd < Gs; dd <<= 1) {
        s += __shfl_xor(s, dd);
        d += __shfl_xor(d, dd);
    }
    if ((lane & (Gs - 1)) == 0) {
        int hh = lane / Gs;
        als[wid * Ht + hh] = s;
        ald[wid * Ht + hh] = d;
    }
}

// ---------------- edge alpha: alpha[t][h] = exp(leaky(als[src]+ald[dst])) --
// edge-flat, coalesced, exp computed ONCE per edge-head (not per lane)
__global__ void k_alpha4(const float* __restrict__ als, const float* __restrict__ ald,
                         const int* __restrict__ csr, const int* __restrict__ dstarr,
                         float* __restrict__ alpha, int M)
{
    int t = blockIdx.x * blockDim.x + threadIdx.x;
    if (t >= M) return;
    int s = csr[t], d = dstarr[t];
    f32x4 a = *(const f32x4*)(als + (size_t)s * 4);
    f32x4 b = *(const f32x4*)(ald + (size_t)d * 4);
    f32x4 o;
#pragma unroll
    for (int h = 0; h < 4; ++h) {
        float l = a[h] + b[h];
        l = l > 0.f ? l : 0.2f * l;
        o[h] = __expf(l);
    }
    *(f32x4*)(alpha + (size_t)t * 4) = o;
}
__global__ void k_alpha1(const float* __restrict__ als, const float* __restrict__ ald,
                         const int* __restrict__ csr, const int* __restrict__ dstarr,
                         float* __restrict__ alpha, int M)
{
    int t = blockIdx.x * blockDim.x + threadIdx.x;
    if (t >= M) return;
    float l = als[csr[t]] + ald[dstarr[t]];
    l = l > 0.f ? l : 0.2f * l;
    alpha[t] = __expf(l);
}

// ---------------- aggr for HC=512, H=4, bf16 h, materialized alpha --------
// Wave = (node, head); 4 edge-groups x 16 lanes; lane owns 8 bf16 (16B).
// Slab-sequential grid (head-major): 2.5 MB distinct h lines per slab,
// L2-resident per XCD. Inner loop: csr + broadcast alpha + h row + FMA only.
template <bool DOELU>
__global__ __launch_bounds__(256) void k_aggr4b(
    const unsigned short* __restrict__ h, const float* __restrict__ alpha,
    const int* __restrict__ off, const int* __restrict__ csr,
    const float* __restrict__ bias,
    unsigned short* __restrict__ outp, int N, int nodeBlocks)
{
    int head = blockIdx.x / nodeBlocks;
    int nb = blockIdx.x - head * nodeBlocks;
    int n = nb * 4 + (threadIdx.x >> 6);
    if (n >= N) return;
    int lane = threadIdx.x & 63;
    int g = lane >> 4;            // edge group 0..3
    int p = lane & 15;            // channel-lane within group
    int s0 = off[n], s1 = off[n + 1];

    float acc[8] = {};
    float den = 0.f;
    const unsigned short* hbase = h + head * 128 + p * 8;
    const float* abase = alpha + head;

    auto stage = [&](int tt, float& a, uint4& q) {
        int ss = csr[tt];
        a = abase[(unsigned)tt << 2];
        q = *(const uint4*)(hbase + ((unsigned)ss << 9));
    };

    int t = s0 + g;
    float ex; uint4 hq;
    bool have = t < s1;
    if (have) stage(t, ex, hq);
    while (have) {
        int tn = t + 4;
        float ex2; uint4 hq2;
        bool have2 = tn < s1;
        if (have2) stage(tn, ex2, hq2);
        den += ex;
        unsigned wds[4] = {hq.x, hq.y, hq.z, hq.w};
#pragma unroll
        for (int wv = 0; wv < 4; ++wv) {
            acc[2 * wv]     += ex * __uint_as_float(wds[wv] << 16);
            acc[2 * wv + 1] += ex * __uint_as_float(wds[wv] & 0xffff0000u);
        }
        t = tn; have = have2; ex = ex2; hq = hq2;
    }

    // reduce across the 4 edge groups
    den += __shfl_xor(den, 16);
    den += __shfl_xor(den, 32);
#pragma unroll
    for (int j = 0; j < 8; ++j) {
        acc[j] += __shfl_xor(acc[j], 16);
        acc[j] += __shfl_xor(acc[j], 32);
    }

    if (g == 0) {
        float inv = 1.f / den;
        int cb = head * 128 + p * 8;
        unsigned ww[4];
#pragma unroll
        for (int wv = 0; wv < 4; ++wv) {
            float v0 = acc[2 * wv] * inv + bias[cb + 2 * wv];
            float v1 = acc[2 * wv + 1] * inv + bias[cb + 2 * wv + 1];
            if (DOELU) {
                v0 = v0 > 0.f ? v0 : expm1f(v0);
                v1 = v1 > 0.f ? v1 : expm1f(v1);
            }
            ww[wv] = (unsigned)f2bf(v0) | ((unsigned)f2bf(v1) << 16);
        }
        uint4 o; o.x = ww[0]; o.y = ww[1]; o.z = ww[2]; o.w = ww[3];
        *((uint4*)(outp + (size_t)n * 512 + cb)) = o;
    }
}

// ---------------- layer-3 aggr (HC=64, H=1, f32 h, materialized alpha) ----
// one wave per dst node; 4 edge-groups x 16 lanes; lane owns 4 f32 (16B)
__global__ __launch_bounds__(256) void k_aggr1b(
    const float* __restrict__ h, const float* __restrict__ alpha,
    const int* __restrict__ off, const int* __restrict__ csr,
    const float* __restrict__ bias,
    float* __restrict__ outp, int N)
{
    int n = blockIdx.x * (blockDim.x >> 6) + (threadIdx.x >> 6);
    if (n >= N) return;
    int lane = threadIdx.x & 63;
    int g = lane >> 4;        // edge group 0..3
    int p = lane & 15;        // channel-lane within group
    int s0 = off[n], s1 = off[n + 1];

    float acc[4] = {};
    float den = 0.f;
    const float* hbase = h + p * 4;

    auto stage = [&](int tt, float& a, uint4& q) {
        int ss = csr[tt];
        a = alpha[tt];
        q = *(const uint4*)(hbase + ((unsigned)ss << 6));
    };
    int t = s0 + g;
    float ex; uint4 hq;
    bool have = t < s1;
    if (have) stage(t, ex, hq);
    while (have) {
        int tn = t + 4;
        float ex2; uint4 hq2;
        bool have2 = tn < s1;
        if (have2) stage(tn, ex2, hq2);
        den += ex;
        acc[0] += ex * __uint_as_float(hq.x);
        acc[1] += ex * __uint_as_float(hq.y);
        acc[2] += ex * __uint_as_float(hq.z);
        acc[3] += ex * __uint_as_float(hq.w);
        t = tn; have = have2; ex = ex2; hq = hq2;
    }

    den += __shfl_xor(den, 16);
    den += __shfl_xor(den, 32);
#pragma unroll
    for (int j = 0; j < 4; ++j) {
        acc[j] += __shfl_xor(acc[j], 16);
        acc[j] += __shfl_xor(acc[j], 32);
    }
    if (g == 0) {
        float inv = 1.f / den;
        f32x4 o;
#pragma unroll
        for (int j = 0; j < 4; ++j)
            o[j] = acc[j] * inv + bias[p * 4 + j];
        *((f32x4*)(outp + (size_t)n * 64 + p * 4)) = o;
    }
}

// --------------------------------------------------------------------------
extern "C" void kernel_launch(void* const* d_in, const int* in_sizes, int n_in,
                              void* d_out, int out_size, void* d_ws, size_t ws_size,
                              hipStream_t stream)
{
    const float* x   = (const float*)d_in[0];
    const int*   ei  = (const int*)d_in[1];
    const float* W1  = (const float*)d_in[2];
    const float* as1 = (const float*)d_in[3];
    const float* ad1 = (const float*)d_in[4];
    const float* b1  = (const float*)d_in[5];
    const float* W2  = (const float*)d_in[6];
    const float* as2 = (const float*)d_in[7];
    const float* ad2 = (const float*)d_in[8];
    const float* b2  = (const float*)d_in[9];
    const float* W3  = (const float*)d_in[10];
    const float* as3 = (const float*)d_in[11];
    const float* ad3 = (const float*)d_in[12];
    const float* b3  = (const float*)d_in[13];

    const int DIN = 256, HC = 512, DOUT = 64;
    int N = in_sizes[0] / DIN;
    int E = in_sizes[1] / 2;
    int M = E + N;  // total CSR slots incl. self-loops

    // workspace carve-up
    char* w = (char*)d_ws;
    auto alloc = [&](size_t bytes) -> char* {
        char* p = w;
        w += (bytes + 255) & ~(size_t)255;
        return p;
    };
    int* deg    = (int*)alloc((size_t)N * 4);
    int* cur    = (int*)alloc((size_t)N * 4);
    int* off    = (int*)alloc((size_t)(N + 1) * 4);
    int* csr    = (int*)alloc((size_t)M * 4);
    int* dstarr = (int*)alloc((size_t)M * 4);
    unsigned short* W1T = (unsigned short*)alloc((size_t)HC * DIN * 2);
    unsigned short* W2T = (unsigned short*)alloc((size_t)HC * HC * 2);
    unsigned short* W3T = (unsigned short*)alloc((size_t)DOUT * HC * 2);
    unsigned short* xb  = (unsigned short*)alloc((size_t)N * DIN * 2);  // bf16 GEMM A (layer1)
    unsigned short* act = (unsigned short*)alloc((size_t)N * HC * 2);   // bf16 activations
    unsigned short* hb  = (unsigned short*)alloc((size_t)N * HC * 2);   // bf16 h (layers 1-2)
    float* hbuf  = (float*)alloc((size_t)N * DOUT * 4);                 // f32 h (layer 3)
    float* als   = (float*)alloc((size_t)N * 4 * 4);
    float* ald   = (float*)alloc((size_t)N * 4 * 4);
    float* alpha = (float*)alloc((size_t)M * 4 * 4);                    // per-edge exp, 4 heads

    // ---- prep (transposes + cvt + deg init), then CSR ----
    int prep_total = DIN * HC + HC * HC + HC * DOUT + N * DIN + N;
    k_prep<<<(prep_total + 255) / 256, 256, 0, stream>>>(
        W1, W1T, W2, W2T, W3, W3T, x, xb, deg, DIN, HC, DOUT, N);
    k_hist<<<(E + 255) / 256, 256, 0, stream>>>(ei, E, deg);
    k_scan<<<1, 1024, 0, stream>>>(deg, off, cur, N);
    k_fill<<<(M + 255) / 256, 256, 0, stream>>>(ei, E, N, cur, csr, dstarr);

    int tiles_m = (N + 63) / 64;
    auto gemm_blocks = [&](int tn) { return (tiles_m * tn + 3) / 4; };
    int nwave_blocks = (N + 3) / 4;
    int nodeBlocks = (N + 3) / 4;
    int edge_blocks = (M + 255) / 256;

    // ---- layer 1 ----
    k_gemm<true><<<gemm_blocks(HC / 64), 256, 0, stream>>>(xb, W1T, hb, N, DIN, HC, HC / 64);
    k_al<512, 4, true><<<nwave_blocks, 256, 0, stream>>>(hb, as1, ad1, als, ald, N);
    k_alpha4<<<edge_blocks, 256, 0, stream>>>(als, ald, csr, dstarr, alpha, M);
    k_aggr4b<true><<<4 * nodeBlocks, 256, 0, stream>>>(hb, alpha, off, csr, b1, act, N, nodeBlocks);

    // ---- layer 2 ----
    k_gemm<true><<<gemm_blocks(HC / 64), 256, 0, stream>>>(act, W2T, hb, N, HC, HC, HC / 64);
    k_al<512, 4, true><<<nwave_blocks, 256, 0, stream>>>(hb, as2, ad2, als, ald, N);
    k_alpha4<<<edge_blocks, 256, 0, stream>>>(als, ald, csr, dstarr, alpha, M);
    k_aggr4b<true><<<4 * nodeBlocks, 256, 0, stream>>>(hb, alpha, off, csr, b2, act, N, nodeBlocks);

    // ---- layer 3 ----
    k_gemm<false><<<gemm_blocks(1), 256, 0, stream>>>(act, W3T, hbuf, N, HC, DOUT, 1);
    k_al<64, 1, false><<<nwave_blocks, 256, 0, stream>>>(hbuf, as3, ad3, als, ald, N);
    k_alpha1<<<edge_blocks, 256, 0, stream>>>(als, ald, csr, dstarr, alpha, M);
    k_aggr1b<<<nwave_blocks, 256, 0, stream>>>(hbuf, alpha, off, csr, b3, (float*)d_out, N);
}

// Round 10
// 335.014 us; speedup vs baseline: 1.1028x; 1.0429x over previous
//
#include <hip/hip_runtime.h>

typedef short bf16x8 __attribute__((ext_vector_type(8)));
typedef float f32x4 __attribute__((ext_vector_type(4)));

__device__ __forceinline__ unsigned short f2bf(float f) {
    unsigned u = __float_as_uint(f);
    unsigned r = (u + 0x7fffu + ((u >> 16) & 1u)) >> 16;
    return (unsigned short)r;
}

// ---------------- CSR build ----------------
__global__ void k_hist(const int* __restrict__ ei, int E, int* deg) {
    int e = blockIdx.x * blockDim.x + threadIdx.x;
    if (e < E) atomicAdd(&deg[ei[E + e]], 1);
}
// scan with implicit +1 per node (self-loop)
__global__ void k_scan(const int* __restrict__ deg, int* __restrict__ off,
                       int* __restrict__ cur, int N) {
    __shared__ int sums[1024];
    int t = threadIdx.x;
    int chunk = (N + 1023) >> 10;
    int lo = t * chunk;
    int hi = lo + chunk; if (hi > N) hi = N;
    if (lo > N) lo = N;
    int s = 0;
    for (int i = lo; i < hi; ++i) s += deg[i] + 1;
    sums[t] = s;
    __syncthreads();
    for (int dd = 1; dd < 1024; dd <<= 1) {
        int v = (t >= dd) ? sums[t - dd] : 0;
        __syncthreads();
        sums[t] += v;
        __syncthreads();
    }
    int run = sums[t] - s;  // exclusive prefix
    for (int i = lo; i < hi; ++i) { off[i] = run; cur[i] = run; run += deg[i] + 1; }
    if (t == 1023) off[N] = run;
}
__global__ void k_fill(const int* __restrict__ ei, int E, int N,
                       int* cur, int* __restrict__ csr, int* __restrict__ dstarr) {
    int i = blockIdx.x * blockDim.x + threadIdx.x;
    if (i < E) {
        int s = ei[i], d = ei[E + i];
        int pos = atomicAdd(&cur[d], 1);
        csr[pos] = s;
        dstarr[pos] = d;
    } else if (i < E + N) {
        int nn = i - E;
        int pos = atomicAdd(&cur[nn], 1);
        csr[pos] = nn;
        dstarr[pos] = nn;
    }
}

// ---------------- fused prep: W transposes (f32->bf16), x cvt ----
__global__ void k_prep(const float* __restrict__ W1, unsigned short* __restrict__ W1T,
                       const float* __restrict__ W2, unsigned short* __restrict__ W2T,
                       const float* __restrict__ W3, unsigned short* __restrict__ W3T,
                       const float* __restrict__ x, unsigned short* __restrict__ xb,
                       int DIN, int HC, int DOUT, int N)
{
    int i = blockIdx.x * blockDim.x + threadIdx.x;
    int n1 = DIN * HC;            // W1: [DIN,HC] -> [HC,DIN]
    int n2 = n1 + HC * HC;
    int n3 = n2 + HC * DOUT;
    int n4 = n3 + N * DIN;
    if (i < n1) {
        int k = i / HC, n = i - k * HC;
        W1T[n * DIN + k] = f2bf(W1[i]);
    } else if (i < n2) {
        int j = i - n1;
        int k = j / HC, n = j - k * HC;
        W2T[n * HC + k] = f2bf(W2[j]);
    } else if (i < n3) {
        int j = i - n2;
        int k = j / DOUT, n = j - k * DOUT;
        W3T[n * HC + k] = f2bf(W3[j]);
    } else if (i < n4) {
        int j = i - n3;
        xb[j] = f2bf(x[j]);
    }
}

// ---------------- GEMM: D[M,Nc] = A[M,K] (bf16) @ BT[Nc,K]^T (bf16) ----
// one wave computes a 64x64 tile; register double-buffered K loop
template <bool OUTBF>
__global__ __launch_bounds__(256) void k_gemm(
    const unsigned short* __restrict__ A, const unsigned short* __restrict__ BT,
    void* __restrict__ D, int M, int K, int Nc, int tiles_n)
{
    int wid = blockIdx.x * (blockDim.x >> 6) + (threadIdx.x >> 6);
    int tiles_m = (M + 63) >> 6;
    if (wid >= tiles_m * tiles_n) return;
    int lane = threadIdx.x & 63;
    int tm = wid / tiles_n, tn = wid - tm * tiles_n;
    int m0 = tm << 6, n0 = tn << 6;
    int r = lane & 15, q = lane >> 4;

    const unsigned short* Arow[4];
    const unsigned short* Brow[4];
#pragma unroll
    for (int i = 0; i < 4; ++i) {
        int row = m0 + 16 * i + r; row = row < M ? row : M - 1;
        Arow[i] = A + (size_t)row * K + q * 8;
        Brow[i] = BT + (size_t)(n0 + 16 * i + r) * K + q * 8;
    }

    f32x4 acc[4][4] = {};
    bf16x8 a[4], b[4], a2[4], b2[4];
#pragma unroll
    for (int i = 0; i < 4; ++i) {
        a[i] = *(const bf16x8*)(Arow[i]);
        b[i] = *(const bf16x8*)(Brow[i]);
    }
    for (int k0 = 0; k0 < K; k0 += 32) {
        int kn = k0 + 32;
        if (kn < K) {
#pragma unroll
            for (int i = 0; i < 4; ++i) {
                a2[i] = *(const bf16x8*)(Arow[i] + kn);
                b2[i] = *(const bf16x8*)(Brow[i] + kn);
            }
        }
#pragma unroll
        for (int i = 0; i < 4; ++i)
#pragma unroll
            for (int j = 0; j < 4; ++j)
                acc[i][j] = __builtin_amdgcn_mfma_f32_16x16x32_bf16(a[i], b[j], acc[i][j], 0, 0, 0);
        if (kn < K) {
#pragma unroll
            for (int i = 0; i < 4; ++i) { a[i] = a2[i]; b[i] = b2[i]; }
        }
    }
#pragma unroll
    for (int i = 0; i < 4; ++i) {
        int rowb = m0 + 16 * i + q * 4;
#pragma unroll
        for (int rr = 0; rr < 4; ++rr) {
            int row = rowb + rr;
            if (row < M) {
#pragma unroll
                for (int j = 0; j < 4; ++j) {
                    int col = n0 + 16 * j + r;
                    if (OUTBF)
                        ((unsigned short*)D)[(size_t)row * Nc + col] = f2bf(acc[i][j][rr]);
                    else
                        ((float*)D)[(size_t)row * Nc + col] = acc[i][j][rr];
                }
            }
        }
    }
}

// ---------------- attention logits per node: al_s, al_d -------------------
template <int HCt, int Ht, bool INBF>
__global__ __launch_bounds__(256) void k_al(
    const void* __restrict__ h, const float* __restrict__ asrc,
    const float* __restrict__ adst,
    float* __restrict__ als, float* __restrict__ ald, int N)
{
    int wid = blockIdx.x * (blockDim.x >> 6) + (threadIdx.x >> 6);
    if (wid >= N) return;
    int lane = threadIdx.x & 63;
    const int CH = HCt / 64;
    const int Gs = 64 / Ht;  // lanes per head
    float s = 0.f, d = 0.f;
    if constexpr (INBF) {
        // CH == 8: one 16B load of 8 bf16
        const uint4* hr = (const uint4*)((const unsigned short*)h + (size_t)wid * HCt) + lane;
        uint4 hv = *hr;
        unsigned wds[4] = {hv.x, hv.y, hv.z, hv.w};
        const f32x4* as4 = (const f32x4*)(asrc + lane * 8);
        const f32x4* ad4 = (const f32x4*)(adst + lane * 8);
        f32x4 av0 = as4[0], av1 = as4[1], dv0 = ad4[0], dv1 = ad4[1];
        float hf[8];
#pragma unroll
        for (int wv = 0; wv < 4; ++wv) {
            hf[2 * wv]     = __uint_as_float(wds[wv] << 16);
            hf[2 * wv + 1] = __uint_as_float(wds[wv] & 0xffff0000u);
        }
#pragma unroll
        for (int j = 0; j < 4; ++j) {
            s += hf[j] * av0[j] + hf[4 + j] * av1[j];
            d += hf[j] * dv0[j] + hf[4 + j] * dv1[j];
        }
    } else {
        const float* hr = (const float*)h + (size_t)wid * HCt + lane * CH;
#pragma unroll
        for (int j = 0; j < CH; ++j) {
            float hv = hr[j];
            int ch = lane * CH + j;
            s += hv * asrc[ch];
            d += hv * adst[ch];
        }
    }
#pragma unroll
    for (int dd = 1; dd < Gs; dd <<= 1) {
        s += __shfl_xor(s, dd);
        d += __shfl_xor(d, dd);
    }
    if ((lane & (Gs - 1)) == 0) {
        int hh = lane / Gs;
        als[wid * Ht + hh] = s;
        ald[wid * Ht + hh] = d;
    }
}

// ---------------- edge alpha, SoA head planes: alpha[h*M + t] -------------
__global__ void k_alpha4(const float* __restrict__ als, const float* __restrict__ ald,
                         const int* __restrict__ csr, const int* __restrict__ dstarr,
                         float* __restrict__ alpha, int M)
{
    int t = blockIdx.x * blockDim.x + threadIdx.x;
    if (t >= M) return;
    int s = csr[t], d = dstarr[t];
    f32x4 a = *(const f32x4*)(als + (size_t)s * 4);
    f32x4 b = *(const f32x4*)(ald + (size_t)d * 4);
#pragma unroll
    for (int h = 0; h < 4; ++h) {
        float l = a[h] + b[h];
        l = l > 0.f ? l : 0.2f * l;
        alpha[(size_t)h * M + t] = __expf(l);
    }
}

// ---------------- aggr for HC=512, H=4, bf16 h, SoA alpha -----------------
// Wave = (node, head); 4 edge-groups x 16 lanes; lane owns 8 bf16 (16B).
// Slab-sequential grid (head-major): 2.5 MB distinct h lines per slab,
// L2-resident per XCD. Ping-pong depth-2 pipeline (no copy chain).
template <bool DOELU>
__global__ __launch_bounds__(256) void k_aggr4b(
    const unsigned short* __restrict__ h, const float* __restrict__ alpha,
    const int* __restrict__ off, const int* __restrict__ csr,
    const float* __restrict__ bias,
    unsigned short* __restrict__ outp, int N, int nodeBlocks, int M)
{
    int head = blockIdx.x / nodeBlocks;
    int nb = blockIdx.x - head * nodeBlocks;
    int n = nb * 4 + (threadIdx.x >> 6);
    if (n >= N) return;
    int lane = threadIdx.x & 63;
    int g = lane >> 4;            // edge group 0..3
    int p = lane & 15;            // channel-lane within group
    int s0 = off[n], s1 = off[n + 1];

    float acc[8] = {};
    float den = 0.f;
    const unsigned short* hbase = h + head * 128 + p * 8;
    const float* abase = alpha + (size_t)head * M;

    auto stage = [&](int tt, float& a, uint4& q) {
        int ss = csr[tt];
        a = abase[tt];
        q = *(const uint4*)(hbase + ((unsigned)ss << 9));
    };
    auto consume = [&](float a, const uint4& q) {
        den += a;
        unsigned wds[4] = {q.x, q.y, q.z, q.w};
#pragma unroll
        for (int wv = 0; wv < 4; ++wv) {
            acc[2 * wv]     += a * __uint_as_float(wds[wv] << 16);
            acc[2 * wv + 1] += a * __uint_as_float(wds[wv] & 0xffff0000u);
        }
    };

    int t = s0 + g;
    float exA, exB; uint4 hqA, hqB;
    if (t < s1) {
        stage(t, exA, hqA);
        for (;;) {
            int t1 = t + 4;
            bool h1 = t1 < s1;
            if (h1) stage(t1, exB, hqB);
            consume(exA, hqA);
            if (!h1) break;
            int t2 = t1 + 4;
            bool h2 = t2 < s1;
            if (h2) stage(t2, exA, hqA);
            consume(exB, hqB);
            if (!h2) break;
            t = t2;
        }
    }

    // reduce across the 4 edge groups
    den += __shfl_xor(den, 16);
    den += __shfl_xor(den, 32);
#pragma unroll
    for (int j = 0; j < 8; ++j) {
        acc[j] += __shfl_xor(acc[j], 16);
        acc[j] += __shfl_xor(acc[j], 32);
    }

    if (g == 0) {
        float inv = 1.f / den;
        int cb = head * 128 + p * 8;
        unsigned ww[4];
#pragma unroll
        for (int wv = 0; wv < 4; ++wv) {
            float v0 = acc[2 * wv] * inv + bias[cb + 2 * wv];
            float v1 = acc[2 * wv + 1] * inv + bias[cb + 2 * wv + 1];
            if (DOELU) {
                v0 = v0 > 0.f ? v0 : expm1f(v0);
                v1 = v1 > 0.f ? v1 : expm1f(v1);
            }
            ww[wv] = (unsigned)f2bf(v0) | ((unsigned)f2bf(v1) << 16);
        }
        uint4 o; o.x = ww[0]; o.y = ww[1]; o.z = ww[2]; o.w = ww[3];
        *((uint4*)(outp + (size_t)n * 512 + cb)) = o;
    }
}

// ---------------- layer-3 aggr (HC=64, H=1, f32 h, inline alpha) ----------
// als table is 40KB (L1/L2-resident) -> inline logit+exp is cheap here.
__global__ __launch_bounds__(256) void k_aggr1b(
    const float* __restrict__ h, const float* __restrict__ als,
    const float* __restrict__ aldv, const int* __restrict__ off,
    const int* __restrict__ csr, const float* __restrict__ bias,
    float* __restrict__ outp, int N)
{
    int n = blockIdx.x * (blockDim.x >> 6) + (threadIdx.x >> 6);
    if (n >= N) return;
    int lane = threadIdx.x & 63;
    int g = lane >> 4;        // edge group 0..3
    int p = lane & 15;        // channel-lane within group
    int s0 = off[n], s1 = off[n + 1];
    float aldh = aldv[n];

    float acc[4] = {};
    float den = 0.f;
    const float* hbase = h + p * 4;

    auto stage = [&](int tt, float& a, uint4& q) {
        int ss = csr[tt];
        float l = als[ss] + aldh;
        l = l > 0.f ? l : 0.2f * l;
        a = __expf(l);
        q = *(const uint4*)(hbase + ((unsigned)ss << 6));
    };
    auto consume = [&](float a, const uint4& q) {
        den += a;
        acc[0] += a * __uint_as_float(q.x);
        acc[1] += a * __uint_as_float(q.y);
        acc[2] += a * __uint_as_float(q.z);
        acc[3] += a * __uint_as_float(q.w);
    };

    int t = s0 + g;
    float exA, exB; uint4 hqA, hqB;
    if (t < s1) {
        stage(t, exA, hqA);
        for (;;) {
            int t1 = t + 4;
            bool h1 = t1 < s1;
            if (h1) stage(t1, exB, hqB);
            consume(exA, hqA);
            if (!h1) break;
            int t2 = t1 + 4;
            bool h2 = t2 < s1;
            if (h2) stage(t2, exA, hqA);
            consume(exB, hqB);
            if (!h2) break;
            t = t2;
        }
    }

    den += __shfl_xor(den, 16);
    den += __shfl_xor(den, 32);
#pragma unroll
    for (int j = 0; j < 4; ++j) {
        acc[j] += __shfl_xor(acc[j], 16);
        acc[j] += __shfl_xor(acc[j], 32);
    }
    if (g == 0) {
        float inv = 1.f / den;
        f32x4 o;
#pragma unroll
        for (int j = 0; j < 4; ++j)
            o[j] = acc[j] * inv + bias[p * 4 + j];
        *((f32x4*)(outp + (size_t)n * 64 + p * 4)) = o;
    }
}

// --------------------------------------------------------------------------
extern "C" void kernel_launch(void* const* d_in, const int* in_sizes, int n_in,
                              void* d_out, int out_size, void* d_ws, size_t ws_size,
                              hipStream_t stream)
{
    const float* x   = (const float*)d_in[0];
    const int*   ei  = (const int*)d_in[1];
    const float* W1  = (const float*)d_in[2];
    const float* as1 = (const float*)d_in[3];
    const float* ad1 = (const float*)d_in[4];
    const float* b1  = (const float*)d_in[5];
    const float* W2  = (const float*)d_in[6];
    const float* as2 = (const float*)d_in[7];
    const float* ad2 = (const float*)d_in[8];
    const float* b2  = (const float*)d_in[9];
    const float* W3  = (const float*)d_in[10];
    const float* as3 = (const float*)d_in[11];
    const float* ad3 = (const float*)d_in[12];
    const float* b3  = (const float*)d_in[13];

    const int DIN = 256, HC = 512, DOUT = 64;
    int N = in_sizes[0] / DIN;
    int E = in_sizes[1] / 2;
    int M = E + N;  // total CSR slots incl. self-loops

    // workspace carve-up
    char* w = (char*)d_ws;
    auto alloc = [&](size_t bytes) -> char* {
        char* p = w;
        w += (bytes + 255) & ~(size_t)255;
        return p;
    };
    int* deg    = (int*)alloc((size_t)N * 4);
    int* cur    = (int*)alloc((size_t)N * 4);
    int* off    = (int*)alloc((size_t)(N + 1) * 4);
    int* csr    = (int*)alloc((size_t)M * 4);
    int* dstarr = (int*)alloc((size_t)M * 4);
    unsigned short* W1T = (unsigned short*)alloc((size_t)HC * DIN * 2);
    unsigned short* W2T = (unsigned short*)alloc((size_t)HC * HC * 2);
    unsigned short* W3T = (unsigned short*)alloc((size_t)DOUT * HC * 2);
    unsigned short* xb  = (unsigned short*)alloc((size_t)N * DIN * 2);  // bf16 GEMM A (layer1)
    unsigned short* act = (unsigned short*)alloc((size_t)N * HC * 2);   // bf16 activations
    unsigned short* hb  = (unsigned short*)alloc((size_t)N * HC * 2);   // bf16 h (layers 1-2)
    float* hbuf  = (float*)alloc((size_t)N * DOUT * 4);                 // f32 h (layer 3)
    float* als   = (float*)alloc((size_t)N * 4 * 4);
    float* ald   = (float*)alloc((size_t)N * 4 * 4);
    float* alpha = (float*)alloc((size_t)M * 4 * 4);                    // SoA: 4 planes of M

    // ---- CSR build + prep ----
    hipMemsetAsync(deg, 0, (size_t)N * 4, stream);
    k_hist<<<(E + 255) / 256, 256, 0, stream>>>(ei, E, deg);
    int prep_total = DIN * HC + HC * HC + HC * DOUT + N * DIN;
    k_prep<<<(prep_total + 255) / 256, 256, 0, stream>>>(
        W1, W1T, W2, W2T, W3, W3T, x, xb, DIN, HC, DOUT, N);
    k_scan<<<1, 1024, 0, stream>>>(deg, off, cur, N);
    k_fill<<<(M + 255) / 256, 256, 0, stream>>>(ei, E, N, cur, csr, dstarr);

    int tiles_m = (N + 63) / 64;
    auto gemm_blocks = [&](int tn) { return (tiles_m * tn + 3) / 4; };
    int nwave_blocks = (N + 3) / 4;
    int nodeBlocks = (N + 3) / 4;
    int edge_blocks = (M + 255) / 256;

    // ---- layer 1 ----
    k_gemm<true><<<gemm_blocks(HC / 64), 256, 0, stream>>>(xb, W1T, hb, N, DIN, HC, HC / 64);
    k_al<512, 4, true><<<nwave_blocks, 256, 0, stream>>>(hb, as1, ad1, als, ald, N);
    k_alpha4<<<edge_blocks, 256, 0, stream>>>(als, ald, csr, dstarr, alpha, M);
    k_aggr4b<true><<<4 * nodeBlocks, 256, 0, stream>>>(hb, alpha, off, csr, b1, act, N, nodeBlocks, M);

    // ---- layer 2 ----
    k_gemm<true><<<gemm_blocks(HC / 64), 256, 0, stream>>>(act, W2T, hb, N, HC, HC, HC / 64);
    k_al<512, 4, true><<<nwave_blocks, 256, 0, stream>>>(hb, as2, ad2, als, ald, N);
    k_alpha4<<<edge_blocks, 256, 0, stream>>>(als, ald, csr, dstarr, alpha, M);
    k_aggr4b<true><<<4 * nodeBlocks, 256, 0, stream>>>(hb, alpha, off, csr, b2, act, N, nodeBlocks, M);

    // ---- layer 3 ----
    k_gemm<false><<<gemm_blocks(1), 256, 0, stream>>>(act, W3T, hbuf, N, HC, DOUT, 1);
    k_al<64, 1, false><<<nwave_blocks, 256, 0, stream>>>(hbuf, as3, ad3, als, ald, N);
    k_aggr1b<<<nwave_blocks, 256, 0, stream>>>(hbuf, als, ald, off, csr, b3, (float*)d_out, N);
}